// Round 2
// baseline (1017.425 us; speedup 1.0000x reference)
//
#include <hip/hip_runtime.h>
#include <hip/hip_cooperative_groups.h>

namespace cg = cooperative_groups;

#define NPTS 8192
#define NCH 8
#define STRIDE 6144
#define TOTAL 51200
#define FADE 1228
#define SEG 32
#define SEGLEN 256   // NPTS / SEG
#define JB 4         // j's per thread in argmin
#define TEAMS 4      // t-range teams per argmin block
#define TLEN 64      // SEGLEN / TEAMS
#define S1 41
#define S2 37

// ---------------------------------------------------------------------------
// ONE cooperative kernel: setup -> 7x [argmin -> resolve -> smoother] -> merge
// 256 blocks x 1024 threads, grid.sync() between phases. All arithmetic
// bodies are verbatim from the verified multi-kernel version (bit-identical
// FP chains and accumulation order). Constant weights staged to LDS ONCE.
__global__ __launch_bounds__(1024, 4) void k_mega(
        const float* __restrict__ chunks,
        const float* __restrict__ bs_w1, const float* __restrict__ bs_b1,
        const float* __restrict__ bs_w2, const float* __restrict__ bs_b2,
        const float* __restrict__ bs_w3, const float* __restrict__ bs_b3,
        const float* __restrict__ wp_w1, const float* __restrict__ wp_b1,
        const float* __restrict__ wp_w2, const float* __restrict__ wp_b2,
        const float* __restrict__ wp_w3, const float* __restrict__ wp_b3,
        float* __restrict__ out, unsigned long long* ws) {
#pragma clang fp contract(off)
    cg::grid_group grid = cg::this_grid();

    __shared__ float4 sh[SEGLEN];                       // argmin C-segment
    __shared__ unsigned long long pkbuf[TEAMS - 1][1024];
    __shared__ float Wp[780];    // weight-predictor MLP weights
    __shared__ float F[3][44];
    __shared__ float H1[32][S1];
    __shared__ float H2[32][S2];
    __shared__ float W1s[480];   // bs_w1 (32*15)
    __shared__ float B1s[32];
    __shared__ float W2[5120];   // bs_w2 transposed
    __shared__ float B2[32];
    __shared__ float W3s[480];   // bs_w3 linear (3*160)
    __shared__ float B3s[3];

    // workspace layout (identical to multi-kernel version)
    unsigned long long* packed_all = ws;                 // 7*8192 u64
    float* fin      = (float*)(packed_all + (NCH - 1) * NPTS);  // 196608 f32
    float* fused    = fin + NCH * NPTS * 3;              // 24576 f32
    int*   mi       = (int*)(fused + 3 * NPTS);          // 8192 i32
    int*   jmax_all = mi + NPTS;                         // 57344 i32

    int tid = threadIdx.x;
    int bid = blockIdx.x;
    int gtid = bid * 1024 + tid;

    // ---- phase 0: setup (global) ----
    if (gtid < NCH * NPTS * 3) fin[gtid] = chunks[gtid];
    if (gtid < (NCH - 1) * NPTS) {
        jmax_all[gtid] = -1;
        packed_all[gtid] = 0xFFFFFFFFFFFFFFFFull;
    }

    // ---- hoisted block-local constant-weight staging (once per launch) ----
    for (int i = tid; i < 780; i += 1024) {
        float v;
        if (i < 192) v = wp_w1[i];
        else if (i < 224) v = wp_b1[i - 192];
        else if (i < 736) v = wp_w2[i - 224];
        else if (i < 752) v = wp_b2[i - 736];
        else if (i < 768) v = wp_w3[i - 752];
        else v = wp_b3[0];
        Wp[i] = v;
    }
    for (int li = tid; li < 1280; li += 1024) {
        float4 v = ((const float4*)bs_w2)[li];
        int base = li * 4;
#pragma unroll
        for (int u = 0; u < 4; ++u) {
            int idx = base + u;
            int co = idx / 160;
            int r = idx - co * 160;
            int ci = r / 5;
            int k = r - ci * 5;
            W2[(ci * 5 + k) * 32 + co] = (&v.x)[u];
        }
    }
    for (int i = tid; i < 480; i += 1024) { W1s[i] = bs_w1[i]; W3s[i] = bs_w3[i]; }
    if (tid < 32) { B1s[tid] = bs_b1[tid]; B2[tid] = bs_b2[tid]; }
    if (tid < 3)  B3s[tid] = bs_b3[tid];

    grid.sync();

    for (int it = 1; it < NCH; ++it) {
        const float* C = chunks + it * NPTS * 3;
        float* P  = fin + (it - 1) * NPTS * 3;
        float* Pn = fin + it * NPTS * 3;
        unsigned long long* packed = packed_all + (it - 1) * NPTS;
        int* jmax = jmax_all + (it - 1) * NPTS;

        // ===================== argmin =====================
        {
            int bx = bid & 7, by = bid >> 3;
            int lt = tid & 255, team = tid >> 8;
            int k0 = by * SEGLEN;
            if (tid < SEGLEN) {
                int k = k0 + tid;
                float x = C[k * 3 + 0], y = C[k * 3 + 1], z = C[k * 3 + 2];
                float cc = (x * x + y * y) + z * z;
                sh[tid] = make_float4(x, y, z, cc);
            }
            __syncthreads();
            int j0 = bx * (256 * JB) + lt * JB;
            const float4* Pv = (const float4*)(P + j0 * 3);    // 16B-aligned
            float4 a = Pv[0], b = Pv[1], c4 = Pv[2];
            float p0[JB] = {a.x, a.w, b.z, c4.y};
            float p1[JB] = {a.y, b.x, b.w, c4.z};
            float p2[JB] = {a.z, b.y, c4.x, c4.w};
            float pp[JB], best[JB];
            int bt[JB];
            int t0 = team * TLEN;
#pragma unroll
            for (int i = 0; i < JB; ++i) {
                pp[i] = (p0[i] * p0[i] + p1[i] * p1[i]) + p2[i] * p2[i];
                best[i] = 3.4e38f;
                bt[i] = t0;
            }
#pragma unroll 4
            for (int tt = 0; tt < TLEN; ++tt) {
                int t = t0 + tt;
                float4 f = sh[t];
#pragma unroll
                for (int i = 0; i < JB; ++i) {
                    float g = __builtin_fmaf(p2[i], f.z, __builtin_fmaf(p1[i], f.y, p0[i] * f.x));
                    float sadd = pp[i] + f.w;
                    float d = __builtin_fmaf(-2.0f, g, sadd);
                    if (d < best[i]) { best[i] = d; bt[i] = t; }   // strict <: lowest t wins
                }
            }
            unsigned long long pk[JB];
#pragma unroll
            for (int i = 0; i < JB; ++i) {
                unsigned ud = __float_as_uint(best[i]);
                if (ud == 0x80000000u) ud = 0u;                   // -0 -> +0 (bitwise)
                ud = (ud & 0x80000000u) ? ~ud : (ud | 0x80000000u);
                pk[i] = ((unsigned long long)ud << 32)
                      | (unsigned long long)(unsigned)(k0 + bt[i]);
            }
            if (team > 0) {
#pragma unroll
                for (int i = 0; i < JB; ++i) pkbuf[team - 1][lt * JB + i] = pk[i];
            }
            __syncthreads();
            if (team == 0) {
#pragma unroll
                for (int i = 0; i < JB; ++i) {
                    unsigned long long v = pk[i];
                    unsigned long long v1 = pkbuf[0][lt * JB + i];
                    unsigned long long v2 = pkbuf[1][lt * JB + i];
                    unsigned long long v3 = pkbuf[2][lt * JB + i];
                    if (v1 < v) v = v1;
                    if (v2 < v) v = v2;
                    if (v3 < v) v = v3;
                    atomicMin(&packed[j0 + i], v);
                }
            }
        }
        grid.sync();

        // ===================== resolve =====================
        if (tid < 32) {
            int j = bid * 32 + tid;
            int m = (int)(unsigned)(packed[j] & 0xFFFFFFFFull);
            mi[j] = m;
            float x6[6];
            x6[0] = P[j * 3 + 0]; x6[1] = P[j * 3 + 1]; x6[2] = P[j * 3 + 2];
            x6[3] = C[m * 3 + 0]; x6[4] = C[m * 3 + 1]; x6[5] = C[m * 3 + 2];

            float h1[32];
#pragma unroll
            for (int o = 0; o < 32; ++o) {
                float acc = 0.0f;
#pragma unroll
                for (int ci = 0; ci < 6; ++ci) acc = __builtin_fmaf(x6[ci], Wp[o * 6 + ci], acc);
                h1[o] = fmaxf(acc + Wp[192 + o], 0.0f);
            }
            float h2[16];
#pragma unroll
            for (int o = 0; o < 16; ++o) {
                float acc = 0.0f;
#pragma unroll
                for (int ci = 0; ci < 32; ++ci) acc = __builtin_fmaf(h1[ci], Wp[224 + o * 32 + ci], acc);
                h2[o] = fmaxf(acc + Wp[736 + o], 0.0f);
            }
            float acc = 0.0f;
#pragma unroll
            for (int ci = 0; ci < 16; ++ci) acc = __builtin_fmaf(h2[ci], Wp[752 + ci], acc);
            float z = acc + Wp[768];
            float w = 1.0f / (1.0f + expf(-z));
            float omw = 1.0f - w;
#pragma unroll
            for (int e = 0; e < 3; ++e) {
                float t1 = w * x6[e];
                float t2 = omw * x6[3 + e];
                fused[e * NPTS + j] = t1 + t2;
            }
            atomicMax(&jmax[m], j);
        }
        grid.sync();

        // ===================== smoother =====================
        {
            int BASE = bid * 32;
            for (int li = tid; li < 132; li += 1024) {
                int c = li / 44, i = li % 44;
                int t = BASE - 6 + i;
                F[c][i] = (t >= 0 && t < NPTS) ? fused[c * NPTS + t] : 0.0f;
            }
            __syncthreads();

            if (tid < 256) {
                int co = tid >> 3, pg = tid & 7;
                float wr[15];
#pragma unroll
                for (int q = 0; q < 15; ++q) wr[q] = W1s[co * 15 + q];
                float bias = B1s[co];
#pragma unroll
                for (int s = 0; s < 5; ++s) {
                    int i = pg * 5 + s;
                    int t = BASE - 4 + i;
                    float acc = 0.0f;
#pragma unroll
                    for (int k = 0; k < 5; ++k)
#pragma unroll
                        for (int ci = 0; ci < 3; ++ci)
                            acc = __builtin_fmaf(F[ci][i + k], wr[ci * 5 + k], acc);
                    H1[co][i] = (t >= 0 && t < NPTS) ? fmaxf(acc + bias, 0.0f) : 0.0f;
                }
            }
            __syncthreads();

            {
                int cq = tid & 7, pq = tid >> 3;
                if (pq < 18) {
                    int i2 = pq * 2;
                    int co0 = cq * 4;
                    float acc00 = 0.f, acc01 = 0.f, acc02 = 0.f, acc03 = 0.f;
                    float acc10 = 0.f, acc11 = 0.f, acc12 = 0.f, acc13 = 0.f;
                    for (int k = 0; k < 5; ++k) {
#pragma unroll
                        for (int ci = 0; ci < 32; ++ci) {
                            float in0 = H1[ci][i2 + k];
                            float in1 = H1[ci][i2 + k + 1];
                            const float4 wv = *(const float4*)&W2[(ci * 5 + k) * 32 + co0];
                            acc00 = __builtin_fmaf(in0, wv.x, acc00);
                            acc01 = __builtin_fmaf(in0, wv.y, acc01);
                            acc02 = __builtin_fmaf(in0, wv.z, acc02);
                            acc03 = __builtin_fmaf(in0, wv.w, acc03);
                            acc10 = __builtin_fmaf(in1, wv.x, acc10);
                            acc11 = __builtin_fmaf(in1, wv.y, acc11);
                            acc12 = __builtin_fmaf(in1, wv.z, acc12);
                            acc13 = __builtin_fmaf(in1, wv.w, acc13);
                        }
                    }
                    int t0 = BASE - 2 + i2, t1 = t0 + 1;
                    bool ok0 = (t0 >= 0 && t0 < NPTS), ok1 = (t1 >= 0 && t1 < NPTS);
                    H2[co0 + 0][i2]     = ok0 ? fmaxf(acc00 + B2[co0 + 0], 0.0f) : 0.0f;
                    H2[co0 + 1][i2]     = ok0 ? fmaxf(acc01 + B2[co0 + 1], 0.0f) : 0.0f;
                    H2[co0 + 2][i2]     = ok0 ? fmaxf(acc02 + B2[co0 + 2], 0.0f) : 0.0f;
                    H2[co0 + 3][i2]     = ok0 ? fmaxf(acc03 + B2[co0 + 3], 0.0f) : 0.0f;
                    H2[co0 + 0][i2 + 1] = ok1 ? fmaxf(acc10 + B2[co0 + 0], 0.0f) : 0.0f;
                    H2[co0 + 1][i2 + 1] = ok1 ? fmaxf(acc11 + B2[co0 + 1], 0.0f) : 0.0f;
                    H2[co0 + 2][i2 + 1] = ok1 ? fmaxf(acc12 + B2[co0 + 2], 0.0f) : 0.0f;
                    H2[co0 + 3][i2 + 1] = ok1 ? fmaxf(acc13 + B2[co0 + 3], 0.0f) : 0.0f;
                }
            }
            __syncthreads();

            if (tid < 96) {
                int co = tid >> 5, p = tid & 31;
                float acc = 0.0f;
#pragma unroll
                for (int k = 0; k < 5; ++k)
#pragma unroll
                    for (int ci = 0; ci < 32; ++ci)
                        acc = __builtin_fmaf(H2[ci][p + k], W3s[co * 160 + ci * 5 + k], acc);
                float val = acc + B3s[co];
                int jj = BASE + p;
                P[jj * 3 + co] = val;                     // sm written in place
                int kk = mi[jj];
                if (jmax[kk] == jj) Pn[kk * 3 + co] = val;  // unique winner per k
            }
        }
        grid.sync();
    }

    // ===================== merge =====================
    if (gtid < TOTAL) {
        int pos = gtid;
        int imax = pos / STRIDE; if (imax > NCH - 1) imax = NCH - 1;
        int imin = (pos >= NPTS) ? ((pos - NPTS) / STRIDE + 1) : 0;
        float a0 = 0.0f, a1 = 0.0f, a2 = 0.0f, wsum = 0.0f;
        const float kstep = 0.9f / 1227.0f;
        for (int i = imin; i <= imax; ++i) {
            int t = pos - i * STRIDE;
            float cw;
            if (t < FADE)                cw = 0.1f + (float)t * kstep;
            else if (t >= NPTS - FADE)   cw = 1.0f - (float)(t - (NPTS - FADE)) * kstep;
            else                         cw = 1.0f;
            const float* v = fin + (i * NPTS + t) * 3;
            a0 += cw * v[0];
            a1 += cw * v[1];
            a2 += cw * v[2];
            wsum += cw;
        }
        float wm = fmaxf(wsum, 1e-8f);
        out[pos * 3 + 0] = a0 / wm;
        out[pos * 3 + 1] = a1 / wm;
        out[pos * 3 + 2] = a2 / wm;
    }
}

// ---------------------------------------------------------------------------
extern "C" void kernel_launch(void* const* d_in, const int* in_sizes, int n_in,
                              void* d_out, int out_size, void* d_ws, size_t ws_size,
                              hipStream_t stream) {
    const float* chunks = (const float*)d_in[0];
    const float* bs_w1 = (const float*)d_in[1];
    const float* bs_b1 = (const float*)d_in[2];
    const float* bs_w2 = (const float*)d_in[3];
    const float* bs_b2 = (const float*)d_in[4];
    const float* bs_w3 = (const float*)d_in[5];
    const float* bs_b3 = (const float*)d_in[6];
    const float* wp_w1 = (const float*)d_in[7];
    const float* wp_b1 = (const float*)d_in[8];
    const float* wp_w2 = (const float*)d_in[9];
    const float* wp_b2 = (const float*)d_in[10];
    const float* wp_w3 = (const float*)d_in[11];
    const float* wp_b3 = (const float*)d_in[12];
    float* outp = (float*)d_out;
    unsigned long long* wsp = (unsigned long long*)d_ws;

    void* args[] = {
        (void*)&chunks,
        (void*)&bs_w1, (void*)&bs_b1, (void*)&bs_w2, (void*)&bs_b2,
        (void*)&bs_w3, (void*)&bs_b3,
        (void*)&wp_w1, (void*)&wp_b1, (void*)&wp_w2, (void*)&wp_b2,
        (void*)&wp_w3, (void*)&wp_b3,
        (void*)&outp, (void*)&wsp};
    hipLaunchCooperativeKernel((const void*)k_mega, dim3(256), dim3(1024),
                               args, 0, stream);
}

// Round 3
// 667.219 us; speedup vs baseline: 1.5249x; 1.5249x over previous
//
#include <hip/hip_runtime.h>

#define NPTS 8192
#define NCH 8
#define STRIDE 6144
#define TOTAL 51200
#define FADE 1228
#define SEG 32
#define SEGLEN 256   // NPTS / SEG
#define JB 4         // j's per thread in argmin
#define TEAMS 4      // t-range teams per argmin block
#define TLEN 64      // SEGLEN / TEAMS
#define S1 41
#define S2 37

typedef unsigned long long u64;

// ---------------------------------------------------------------------------
// Chunk state is packed u64 per channel: ((winner_j+1) << 32) | f32_bits.
// Raw chunks get tag 0; scatter winners atomicMax with tag jj+1 (max-j wins,
// identical to the old jmax dedupe). Low 32 bits are always the exact value.
__global__ void k_setup(const float* __restrict__ chunks, u64* __restrict__ PK,
                        u64* __restrict__ packed_all) {
    int i = blockIdx.x * 256 + threadIdx.x;            // grid covers 196608
    if (i < NCH * NPTS * 3) PK[i] = (u64)__float_as_uint(chunks[i]);
    if (i < (NCH - 1) * NPTS) packed_all[i] = 0xFFFFFFFFFFFFFFFFull;
}

// ---------------------------------------------------------------------------
// Brute-force argmin over a 256-candidate segment, JB=4 queries per thread.
// d chain bit-identical to the verified version: g = fma(p2,cz, fma(p1,cy,
// p0*cx)); sadd = pp + cc; d = fma(-2, g, sadd). P is read by unpacking the
// low 32 bits of PKprev (exact same float bits as the old float P buffer).
// 1024-thread blocks = 4 t-teams x 256; cross-team lexicographic (d,k) min.
__global__ __launch_bounds__(1024) void k_argmin(const u64* __restrict__ PKprev,
                                                 const float* __restrict__ C,
                                                 u64* __restrict__ packed) {
#pragma clang fp contract(off)
    __shared__ float4 sh[SEGLEN];
    __shared__ u64 pkbuf[TEAMS - 1][1024];
    int tid = threadIdx.x;
    int lt   = tid & 255;          // lane within team (0..255)
    int team = tid >> 8;           // 0..3
    int k0 = blockIdx.y * SEGLEN;
    if (tid < SEGLEN) {
        int k = k0 + tid;
        float x = C[k * 3 + 0], y = C[k * 3 + 1], z = C[k * 3 + 2];
        float cc = (x * x + y * y) + z * z;
        sh[tid] = make_float4(x, y, z, cc);
    }
    __syncthreads();
    int j0 = blockIdx.x * (256 * JB) + lt * JB;
    const u64* Pq = PKprev + (size_t)j0 * 3;           // 12 u64, 96B-aligned
    float p[12];
#pragma unroll
    for (int n = 0; n < 12; ++n) p[n] = __uint_as_float((unsigned)Pq[n]);
    float p0[JB] = {p[0], p[3], p[6], p[9]};
    float p1[JB] = {p[1], p[4], p[7], p[10]};
    float p2[JB] = {p[2], p[5], p[8], p[11]};
    float pp[JB], best[JB];
    int bt[JB];
    int t0 = team * TLEN;
#pragma unroll
    for (int i = 0; i < JB; ++i) {
        pp[i] = (p0[i] * p0[i] + p1[i] * p1[i]) + p2[i] * p2[i];
        best[i] = 3.4e38f;
        bt[i] = t0;
    }
#pragma unroll 4
    for (int tt = 0; tt < TLEN; ++tt) {
        int t = t0 + tt;
        float4 f = sh[t];
#pragma unroll
        for (int i = 0; i < JB; ++i) {
            float g = __builtin_fmaf(p2[i], f.z, __builtin_fmaf(p1[i], f.y, p0[i] * f.x));
            float sadd = pp[i] + f.w;
            float d = __builtin_fmaf(-2.0f, g, sadd);
            if (d < best[i]) { best[i] = d; bt[i] = t; }   // strict <: lowest t wins
        }
    }
    u64 pk[JB];
#pragma unroll
    for (int i = 0; i < JB; ++i) {
        unsigned ud = __float_as_uint(best[i]);
        if (ud == 0x80000000u) ud = 0u;                 // canonicalize -0 -> +0
        ud = (ud & 0x80000000u) ? ~ud : (ud | 0x80000000u);   // order-preserving map
        pk[i] = ((u64)ud << 32) | (u64)(unsigned)(k0 + bt[i]);
    }
    if (team > 0) {
#pragma unroll
        for (int i = 0; i < JB; ++i) pkbuf[team - 1][lt * JB + i] = pk[i];
    }
    __syncthreads();
    if (team == 0) {
#pragma unroll
        for (int i = 0; i < JB; ++i) {
            u64 v = pk[i];
            u64 v1 = pkbuf[0][lt * JB + i];
            u64 v2 = pkbuf[1][lt * JB + i];
            u64 v3 = pkbuf[2][lt * JB + i];
            if (v1 < v) v = v1;
            if (v2 < v) v = v2;
            if (v3 < v) v = v3;
            atomicMin(&packed[j0 + i], v);
        }
    }
}

// ---------------------------------------------------------------------------
// FUSED resolve + smoother + scatter. Each block owns output rows
// [BASE, BASE+32) and recomputes the weight-predictor MLP locally for its
// 44-row halo (bit-identical to the old global fused[] since inputs and op
// order are identical). Epilogue scatters winners into PKnext via packed
// (jj+1)<<32 | bits atomicMax (max-j wins == old jmax dedupe).
__global__ __launch_bounds__(256) void k_rsm(
        const u64* __restrict__ PKprev, const float* __restrict__ C,
        const u64* __restrict__ packed,
        const float* __restrict__ wp_w1, const float* __restrict__ wp_b1,
        const float* __restrict__ wp_w2, const float* __restrict__ wp_b2,
        const float* __restrict__ wp_w3, const float* __restrict__ wp_b3,
        const float* __restrict__ w1g, const float* __restrict__ b1g,
        const float* __restrict__ w2g, const float* __restrict__ b2g,
        const float* __restrict__ w3g, const float* __restrict__ b3g,
        float* __restrict__ finOut, u64* __restrict__ PKnext) {
#pragma clang fp contract(off)
    __shared__ float Wp[780];  // w1[0:192) b1[192:224) w2[224:736) b2[736:752) w3[752:768) b3[768]
    __shared__ float F[3][44];
    __shared__ int   MIs[44];
    __shared__ float H1[32][S1];
    __shared__ float H2[32][S2];
    __shared__ float W2[5120];
    __shared__ float B2[32];
    int tid = threadIdx.x;
    int BASE = blockIdx.x * 32;

    // ---- stage all constant weights ----
    for (int i = tid; i < 780; i += 256) {
        float v;
        if (i < 192) v = wp_w1[i];
        else if (i < 224) v = wp_b1[i - 192];
        else if (i < 736) v = wp_w2[i - 224];
        else if (i < 752) v = wp_b2[i - 736];
        else if (i < 768) v = wp_w3[i - 752];
        else v = wp_b3[0];
        Wp[i] = v;
    }
    for (int li = tid; li < 1280; li += 256) {
        float4 v = ((const float4*)w2g)[li];
        int base = li * 4;
#pragma unroll
        for (int u = 0; u < 4; ++u) {
            int idx = base + u;
            int co = idx / 160;
            int r = idx - co * 160;
            int ci = r / 5;
            int k = r - ci * 5;
            W2[(ci * 5 + k) * 32 + co] = (&v.x)[u];
        }
    }
    if (tid < 32) B2[tid] = b2g[tid];
    __syncthreads();

    // ---- local resolve for the 44-row halo (verbatim MLP body) ----
    if (tid < 44) {
        int jt = BASE - 6 + tid;
        if (jt >= 0 && jt < NPTS) {
            int m = (int)(unsigned)(packed[jt] & 0xFFFFFFFFull);
            MIs[tid] = m;
            float x6[6];
            x6[0] = __uint_as_float((unsigned)PKprev[(size_t)jt * 3 + 0]);
            x6[1] = __uint_as_float((unsigned)PKprev[(size_t)jt * 3 + 1]);
            x6[2] = __uint_as_float((unsigned)PKprev[(size_t)jt * 3 + 2]);
            x6[3] = C[m * 3 + 0]; x6[4] = C[m * 3 + 1]; x6[5] = C[m * 3 + 2];

            float h1[32];
#pragma unroll
            for (int o = 0; o < 32; ++o) {
                float acc = 0.0f;
#pragma unroll
                for (int ci = 0; ci < 6; ++ci) acc = __builtin_fmaf(x6[ci], Wp[o * 6 + ci], acc);
                h1[o] = fmaxf(acc + Wp[192 + o], 0.0f);
            }
            float h2[16];
#pragma unroll
            for (int o = 0; o < 16; ++o) {
                float acc = 0.0f;
#pragma unroll
                for (int ci = 0; ci < 32; ++ci) acc = __builtin_fmaf(h1[ci], Wp[224 + o * 32 + ci], acc);
                h2[o] = fmaxf(acc + Wp[736 + o], 0.0f);
            }
            float acc = 0.0f;
#pragma unroll
            for (int ci = 0; ci < 16; ++ci) acc = __builtin_fmaf(h2[ci], Wp[752 + ci], acc);
            float z = acc + Wp[768];
            float w = 1.0f / (1.0f + expf(-z));
            float omw = 1.0f - w;
#pragma unroll
            for (int e = 0; e < 3; ++e) {
                float t1 = w * x6[e];
                float t2 = omw * x6[3 + e];
                F[e][tid] = t1 + t2;
            }
        } else {
            F[0][tid] = 0.0f; F[1][tid] = 0.0f; F[2][tid] = 0.0f;
            MIs[tid] = 0;
        }
    }
    __syncthreads();

    // ---- smoother layer 1 (verbatim) ----
    {
        int co = tid >> 3, pg = tid & 7;
        float wr[15];
#pragma unroll
        for (int q = 0; q < 15; ++q) wr[q] = w1g[co * 15 + q];
        float bias = b1g[co];
#pragma unroll
        for (int s = 0; s < 5; ++s) {
            int i = pg * 5 + s;
            int t = BASE - 4 + i;
            float acc = 0.0f;
#pragma unroll
            for (int k = 0; k < 5; ++k)
#pragma unroll
                for (int ci = 0; ci < 3; ++ci)
                    acc = __builtin_fmaf(F[ci][i + k], wr[ci * 5 + k], acc);
            H1[co][i] = (t >= 0 && t < NPTS) ? fmaxf(acc + bias, 0.0f) : 0.0f;
        }
    }
    __syncthreads();

    // ---- smoother layer 2 (verbatim) ----
    {
        int cq = tid & 7, pq = tid >> 3;
        if (pq < 18) {
            int i2 = pq * 2;
            int co0 = cq * 4;
            float acc00 = 0.f, acc01 = 0.f, acc02 = 0.f, acc03 = 0.f;
            float acc10 = 0.f, acc11 = 0.f, acc12 = 0.f, acc13 = 0.f;
            for (int k = 0; k < 5; ++k) {
#pragma unroll
                for (int ci = 0; ci < 32; ++ci) {
                    float in0 = H1[ci][i2 + k];
                    float in1 = H1[ci][i2 + k + 1];
                    const float4 wv = *(const float4*)&W2[(ci * 5 + k) * 32 + co0];
                    acc00 = __builtin_fmaf(in0, wv.x, acc00);
                    acc01 = __builtin_fmaf(in0, wv.y, acc01);
                    acc02 = __builtin_fmaf(in0, wv.z, acc02);
                    acc03 = __builtin_fmaf(in0, wv.w, acc03);
                    acc10 = __builtin_fmaf(in1, wv.x, acc10);
                    acc11 = __builtin_fmaf(in1, wv.y, acc11);
                    acc12 = __builtin_fmaf(in1, wv.z, acc12);
                    acc13 = __builtin_fmaf(in1, wv.w, acc13);
                }
            }
            int t0 = BASE - 2 + i2, t1 = t0 + 1;
            bool ok0 = (t0 >= 0 && t0 < NPTS), ok1 = (t1 >= 0 && t1 < NPTS);
            H2[co0 + 0][i2]     = ok0 ? fmaxf(acc00 + B2[co0 + 0], 0.0f) : 0.0f;
            H2[co0 + 1][i2]     = ok0 ? fmaxf(acc01 + B2[co0 + 1], 0.0f) : 0.0f;
            H2[co0 + 2][i2]     = ok0 ? fmaxf(acc02 + B2[co0 + 2], 0.0f) : 0.0f;
            H2[co0 + 3][i2]     = ok0 ? fmaxf(acc03 + B2[co0 + 3], 0.0f) : 0.0f;
            H2[co0 + 0][i2 + 1] = ok1 ? fmaxf(acc10 + B2[co0 + 0], 0.0f) : 0.0f;
            H2[co0 + 1][i2 + 1] = ok1 ? fmaxf(acc11 + B2[co0 + 1], 0.0f) : 0.0f;
            H2[co0 + 2][i2 + 1] = ok1 ? fmaxf(acc12 + B2[co0 + 2], 0.0f) : 0.0f;
            H2[co0 + 3][i2 + 1] = ok1 ? fmaxf(acc13 + B2[co0 + 3], 0.0f) : 0.0f;
        }
    }
    __syncthreads();

    // ---- smoother layer 3 + write + packed scatter ----
    if (tid < 96) {
        int co = tid >> 5, p = tid & 31;
        float wr[160];
        const float4* w3v = (const float4*)(w3g + co * 160);
#pragma unroll
        for (int q = 0; q < 40; ++q) {
            float4 v = w3v[q];
            wr[q * 4 + 0] = v.x; wr[q * 4 + 1] = v.y;
            wr[q * 4 + 2] = v.z; wr[q * 4 + 3] = v.w;
        }
        float acc = 0.0f;
#pragma unroll
        for (int k = 0; k < 5; ++k)
#pragma unroll
            for (int ci = 0; ci < 32; ++ci)
                acc = __builtin_fmaf(H2[ci][p + k], wr[ci * 5 + k], acc);
        float val = acc + b3g[co];
        int jj = BASE + p;
        finOut[jj * 3 + co] = val;
        int kk = MIs[p + 6];
        atomicMax(&PKnext[(size_t)kk * 3 + co],
                  ((u64)(unsigned)(jj + 1) << 32) | (u64)__float_as_uint(val));
    }
}

// ---------------------------------------------------------------------------
// merge: chunks 0..6 from fin (floats), chunk 7 unpacked from PK slot 7.
__global__ void k_merge(const float* __restrict__ fin, const u64* __restrict__ PK7,
                        float* __restrict__ out) {
#pragma clang fp contract(off)
    int pos = blockIdx.x * 256 + threadIdx.x;
    if (pos >= TOTAL) return;
    int imax = pos / STRIDE; if (imax > NCH - 1) imax = NCH - 1;
    int imin = (pos >= NPTS) ? ((pos - NPTS) / STRIDE + 1) : 0;
    float a0 = 0.0f, a1 = 0.0f, a2 = 0.0f, wsum = 0.0f;
    const float kstep = 0.9f / 1227.0f;
    for (int i = imin; i <= imax; ++i) {
        int t = pos - i * STRIDE;
        float cw;
        if (t < FADE)                cw = 0.1f + (float)t * kstep;
        else if (t >= NPTS - FADE)   cw = 1.0f - (float)(t - (NPTS - FADE)) * kstep;
        else                         cw = 1.0f;
        float v0, v1, v2;
        if (i < NCH - 1) {
            const float* v = fin + ((size_t)i * NPTS + t) * 3;
            v0 = v[0]; v1 = v[1]; v2 = v[2];
        } else {
            const u64* q = PK7 + (size_t)t * 3;
            v0 = __uint_as_float((unsigned)q[0]);
            v1 = __uint_as_float((unsigned)q[1]);
            v2 = __uint_as_float((unsigned)q[2]);
        }
        a0 += cw * v0;
        a1 += cw * v1;
        a2 += cw * v2;
        wsum += cw;
    }
    float wm = fmaxf(wsum, 1e-8f);
    out[pos * 3 + 0] = a0 / wm;
    out[pos * 3 + 1] = a1 / wm;
    out[pos * 3 + 2] = a2 / wm;
}

// ---------------------------------------------------------------------------
extern "C" void kernel_launch(void* const* d_in, const int* in_sizes, int n_in,
                              void* d_out, int out_size, void* d_ws, size_t ws_size,
                              hipStream_t stream) {
    const float* chunks = (const float*)d_in[0];
    const float* bs_w1 = (const float*)d_in[1];
    const float* bs_b1 = (const float*)d_in[2];
    const float* bs_w2 = (const float*)d_in[3];
    const float* bs_b2 = (const float*)d_in[4];
    const float* bs_w3 = (const float*)d_in[5];
    const float* bs_b3 = (const float*)d_in[6];
    const float* wp_w1 = (const float*)d_in[7];
    const float* wp_b1 = (const float*)d_in[8];
    const float* wp_w2 = (const float*)d_in[9];
    const float* wp_b2 = (const float*)d_in[10];
    const float* wp_w3 = (const float*)d_in[11];
    const float* wp_b3 = (const float*)d_in[12];

    u64* packed_all = (u64*)d_ws;                    // 7*8192 u64
    u64* PK         = packed_all + (NCH - 1) * NPTS; // 8*8192*3 u64 (packed chunk state)
    float* fin      = (float*)(PK + NCH * NPTS * 3); // 8*8192*3 f32 (slots 0..6 used)
    // total ~2.8 MB

    k_setup<<<768, 256, 0, stream>>>(chunks, PK, packed_all);

    for (int it = 1; it < NCH; ++it) {
        const float* C = chunks + it * NPTS * 3;
        const u64* PKprev = PK + (size_t)(it - 1) * NPTS * 3;
        u64* PKnext = PK + (size_t)it * NPTS * 3;
        u64* packed = packed_all + (it - 1) * NPTS;
        float* finOut = fin + (size_t)(it - 1) * NPTS * 3;

        k_argmin<<<dim3(NPTS / (256 * JB), SEG), 1024, 0, stream>>>(PKprev, C, packed);
        k_rsm<<<256, 256, 0, stream>>>(PKprev, C, packed,
                                       wp_w1, wp_b1, wp_w2, wp_b2, wp_w3, wp_b3,
                                       bs_w1, bs_b1, bs_w2, bs_b2, bs_w3, bs_b3,
                                       finOut, PKnext);
    }

    k_merge<<<200, 256, 0, stream>>>(fin, PK + (size_t)(NCH - 1) * NPTS * 3, (float*)d_out);
}